// Round 5
// baseline (324.864 us; speedup 1.0000x reference)
//
#include <hip/hip_runtime.h>
#include <math.h>

// Problem constants (from reference)
#define HS    250      // sender hidden
#define HRr   100      // receiver hidden
#define VOC   40       // vocab, EOS = 39
#define TMAX  30       // max message length
#define NCLS  262144   // output classes
#define KS    10       // sender blocks (each owns 25 h-rows = 100 gate rows)
#define RPB   25       // h-rows per sender block

typedef unsigned long long ull;

// ws layout. Packed (tag<<32 | float) regions first, 8B-aligned:
//   PK_NH : ull[2][256]  h exchange, double-buffered by tag parity
//   PK_LP : ull[2][400]  logit partials, double-buffered
//   PK_MSG: ull[30*40]   message symbols (written once per slot; tag carries done bit)
// Floats after (byte 20096): WS_SUMS float[64]; WS_HR float[100] @byte 20352 (16B aligned).
#define PKNH(wsp, par) ((ull*)(wsp) + (size_t)(par) * 256)
#define PKLP(wsp, par) ((ull*)(wsp) + 512 + (size_t)(par) * 400)
#define PKMSG(wsp)     ((ull*)(wsp) + 1312)
#define WS_SUMS 5024   // float index
#define WS_HR   5088   // float index (byte 20352, 16B aligned)
#define WS_ZERO_BYTES 20352

#define AST(p, v) __hip_atomic_store((p), (v), __ATOMIC_RELAXED, __HIP_MEMORY_SCOPE_AGENT)
#define ALD(p)    __hip_atomic_load((p), __ATOMIC_RELAXED, __HIP_MEMORY_SCOPE_AGENT)

__device__ __forceinline__ float sigf(float x) { return 1.f / (1.f + expf(-x)); }
__device__ __forceinline__ float lanebc(float v, int l) {
  return __int_as_float(__builtin_amdgcn_readlane(__float_as_int(v), l));
}
__device__ __forceinline__ ull packtv(unsigned tag, float v) {
  return ((ull)tag << 32) | (ull)__float_as_uint(v);
}
__device__ __forceinline__ float lowf(ull w) { return __uint_as_float((unsigned)w); }

#define SENDER_GATES(P, HV)                                   \
  {                                                           \
    _Pragma("unroll")                                         \
    for (int i = 0; i < 64; i += 4) {                         \
      a0 += whh[i    ] * lanebc(HV, i    );                   \
      a1 += whh[i + 1] * lanebc(HV, i + 1);                   \
      a2 += whh[i + 2] * lanebc(HV, i + 2);                   \
      a3 += whh[i + 3] * lanebc(HV, i + 3);                   \
    }                                                         \
    _Pragma("unroll")                                         \
    for (int i = 0; i < 10; i += 2) {                         \
      a0 += wih[i    ] * lanebc(sv, (P) * 10 + i    );        \
      a1 += wih[i + 1] * lanebc(sv, (P) * 10 + i + 1);        \
    }                                                         \
  }

#define RED(x) ((part[(x)] + part[100 + (x)]) + (part[200 + (x)] + part[300 + (x)]))

// ---------------- fused kernel: h0 + sender (blocks 0..9) + receiver (10) --
__global__ __launch_bounds__(512, 2) void k_sender(
    const float* __restrict__ x,
    const float* __restrict__ W_s1,  const float* __restrict__ b_s1,
    const float* __restrict__ gum,
    const float* __restrict__ W_ih1, const float* __restrict__ W_hh1,
    const float* __restrict__ b_ih1, const float* __restrict__ b_hh1,
    const float* __restrict__ W_p,   const float* __restrict__ b_p,
    const float* __restrict__ W_ih2, const float* __restrict__ W_hh2,
    const float* __restrict__ b_ih2, const float* __restrict__ b_hh2,
    float* __restrict__ ws) {
  __shared__ float part[400];
  __shared__ float h0L[32];
  __shared__ float gL[400];     // receiver
  __shared__ float hL[HRr];     // receiver

  const int b    = blockIdx.x;
  const int t0   = threadIdx.x;
  const int lane = t0 & 63;
  const int w    = t0 >> 6;

  if (b < KS) {
    // ================= SENDER =================
    const int p    = w & 3;
    const int lr   = ((w >> 2) << 6) + lane;   // 0..127
    const bool gact = (lr < 100);
    const int gi   = lr / 25, rr = lr % 25;
    const int grow = gi * 250 + b * RPB + rr;  // global gate row

    float whh[64], wih[10], bsum = 0.f;
    if (gact) {
      #pragma unroll
      for (int i = 0; i < 64; i++) {
        int k = p * 64 + i;
        whh[i] = (k < HS) ? W_hh1[(size_t)grow * HS + k] : 0.f;
      }
      #pragma unroll
      for (int i = 0; i < 10; i++) wih[i] = W_ih1[grow * VOC + p * 10 + i];
      bsum = b_ih1[grow] + b_hh1[grow];
    }
    // wave 0: W_p slice (lane j holds W_p[j, b*25 .. +25))
    float wps[RPB];
    if (w == 0) {
      #pragma unroll
      for (int r = 0; r < RPB; r++)
        wps[r] = (lane < VOC) ? W_p[lane * HS + b * RPB + r] : 0.f;
    }
    const float bpv = (lane < VOC) ? b_p[lane] : 0.f;   // all waves (softmax)

    // ---- pre-step: h0 = relu(W_s1 @ x + b_s1), this block's 25 rows ----
    {
      const int nr = (w == 7) ? 4 : 3;
      for (int j = 0; j < nr; ++j) {
        const int r = 3 * w + j;
        const float4* wr = (const float4*)(W_s1 + (size_t)(b * RPB + r) * 4096);
        const float4* xr = (const float4*)x;
        float a0 = 0.f, a1 = 0.f, a2 = 0.f, a3 = 0.f;
        #pragma unroll
        for (int q = 0; q < 16; ++q) {
          float4 w4 = wr[lane + (q << 6)], x4 = xr[lane + (q << 6)];
          a0 += w4.x * x4.x; a1 += w4.y * x4.y; a2 += w4.z * x4.z; a3 += w4.w * x4.w;
        }
        float acc = (a0 + a1) + (a2 + a3);
        #pragma unroll
        for (int o = 32; o; o >>= 1) acc += __shfl_down(acc, o);
        if (lane == 0) h0L[r] = acc + b_s1[b * RPB + r];
      }
    }
    __syncthreads();
    if (w == 0 && lane < RPB) {    // publish h0, tag 1 (parity 1)
      float hn0 = fmaxf(h0L[lane], 0.f);
      AST(&PKNH(ws, 1)[b * RPB + lane], packtv(1u, hn0));
    }

    float c  = 0.f;   // cell state, wave0 lanes<25
    float sv = 0.f;   // current symbol, lane-distributed
    const bool h3v = (192 + lane) < HS;

    for (int s = 0; s <= TMAX; ++s) {
      const unsigned need = (unsigned)(s + 1);
      const int par = (s + 1) & 1;
      float gv = 0.f;
      if (s > 0 && lane < VOC) gv = gum[(s - 1) * VOC + lane];

      // ---- merged self-tag spin: h(s) [4 slots] + lp(s) [10 slots] ----
      const ull* nhp = PKNH(ws, par);
      const ull* lpp = PKLP(ws, par);
      const bool lact = (s > 0) && (lane < VOC);
      ull hw0, hw1, hw2, hw3;
      ull lw0 = 0, lw1 = 0, lw2 = 0, lw3 = 0, lw4 = 0,
          lw5 = 0, lw6 = 0, lw7 = 0, lw8 = 0, lw9 = 0;
      for (;;) {
        hw0 = ALD(&nhp[lane]);
        hw1 = ALD(&nhp[64 + lane]);
        hw2 = ALD(&nhp[128 + lane]);
        hw3 = h3v ? ALD(&nhp[192 + lane]) : ((ull)need << 32);
        bool ok = (unsigned)(hw0 >> 32) == need && (unsigned)(hw1 >> 32) == need &&
                  (unsigned)(hw2 >> 32) == need && (unsigned)(hw3 >> 32) == need;
        if (lact) {
          lw0 = ALD(&lpp[0 * VOC + lane]); lw1 = ALD(&lpp[1 * VOC + lane]);
          lw2 = ALD(&lpp[2 * VOC + lane]); lw3 = ALD(&lpp[3 * VOC + lane]);
          lw4 = ALD(&lpp[4 * VOC + lane]); lw5 = ALD(&lpp[5 * VOC + lane]);
          lw6 = ALD(&lpp[6 * VOC + lane]); lw7 = ALD(&lpp[7 * VOC + lane]);
          lw8 = ALD(&lpp[8 * VOC + lane]); lw9 = ALD(&lpp[9 * VOC + lane]);
          ok = ok && (unsigned)(lw0 >> 32) == need && (unsigned)(lw1 >> 32) == need &&
                     (unsigned)(lw2 >> 32) == need && (unsigned)(lw3 >> 32) == need &&
                     (unsigned)(lw4 >> 32) == need && (unsigned)(lw5 >> 32) == need &&
                     (unsigned)(lw6 >> 32) == need && (unsigned)(lw7 >> 32) == need &&
                     (unsigned)(lw8 >> 32) == need && (unsigned)(lw9 >> 32) == need;
        }
        if (__all(ok)) break;
      }
      float hv0 = lowf(hw0), hv1 = lowf(hw1), hv2 = lowf(hw2);
      float hv3 = h3v ? lowf(hw3) : 0.f;

      // ---- per-wave softmax of step s-1 (redundant across waves) ----
      if (s > 0) {
        float lg = -INFINITY;
        if (lane < VOC) {
          float acc = bpv + gv;
          acc += lowf(lw0); acc += lowf(lw1); acc += lowf(lw2); acc += lowf(lw3);
          acc += lowf(lw4); acc += lowf(lw5); acc += lowf(lw6); acc += lowf(lw7);
          acc += lowf(lw8); acc += lowf(lw9);
          lg = acc;
        }
        float v = lg; int bi = lane;
        #pragma unroll
        for (int o = 32; o; o >>= 1) {      // first-max argmax (ties -> lower lane)
          float ov = __shfl_down(v, o);
          int   oi = __shfl_down(bi, o);
          if (ov > v) { v = ov; bi = oi; }
        }
        float m  = __shfl(v, 0);
        int  idx = __shfl(bi, 0);
        float e = (lane < VOC) ? expf(lg - m) : 0.f;
        float ssum = e;
        #pragma unroll
        for (int o = 32; o; o >>= 1) ssum += __shfl_down(ssum, o);
        ssum = __shfl(ssum, 0);
        float soft = e / ssum;
        float hard = (lane == idx) ? 1.f : 0.f;
        float st   = (hard + soft) - soft;           // exact ST forward ordering
        const bool last = (s - 1 == TMAX - 1);
        float emit = last ? ((lane == VOC - 1) ? 1.f : 0.f) : st;
        const bool done = (idx == VOC - 1) || last;
        if (b == 0 && w == 0 && lane < VOC)
          AST(&PKMSG(ws)[(s - 1) * VOC + lane],
              packtv((unsigned)s | (done ? 0x10000u : 0u), emit));
        sv = (lane < VOC) ? emit : 0.f;
        if (done) break;                             // uniform across all waves/blocks
      }

      // ---- gate partials: 100 rows x k-slice, all 8 waves ----
      if (gact) {
        float a0 = bsum, a1 = 0.f, a2 = 0.f, a3 = 0.f;
        if      (p == 0) SENDER_GATES(0, hv0)
        else if (p == 1) SENDER_GATES(1, hv1)
        else if (p == 2) SENDER_GATES(2, hv2)
        else             SENDER_GATES(3, hv3)
        part[p * 100 + lr] = (a0 + a1) + (a2 + a3);
      }
      __syncthreads();   // the ONLY barrier per step

      // ---- wave-0: reduce, h/c update, logit partial, publish tag s+2 ----
      // Safety: publish stores data-depend on the part[] reads; other waves
      // resume writing part[] only after observing tag s+2 (spin), so no
      // second barrier is needed.
      if (w == 0) {
        float gi_ = RED(lane < RPB ? lane : 0);
        float gf_ = RED(25 + (lane < RPB ? lane : 0));
        float gg_ = RED(50 + (lane < RPB ? lane : 0));
        float go_ = RED(75 + (lane < RPB ? lane : 0));
        float ig = sigf(gi_), fg = sigf(gf_), gg = tanhf(gg_), og = sigf(go_);
        float cn = fg * c + ig * gg; c = cn;
        float hn = og * tanhf(cn);
        float lpsum = 0.f;
        #pragma unroll
        for (int r = 0; r < RPB; ++r) lpsum += wps[r] * lanebc(hn, r);
        const unsigned nt = (unsigned)(s + 2);
        const int np = (s + 2) & 1;
        if (lane < RPB) AST(&PKNH(ws, np)[b * RPB + lane], packtv(nt, hn));
        if (lane < VOC) AST(&PKLP(ws, np)[b * VOC + lane], packtv(nt, lpsum));
      }
    }
  } else {
    // ================= RECEIVER (concurrent consumer) =================
    const bool act = (t0 < 400);
    float wih2[VOC], whh2[HRr], bsum2 = 0.f;
    if (act) {
      #pragma unroll
      for (int i = 0; i < VOC; i++) wih2[i] = W_ih2[t0 * VOC + i];
      #pragma unroll
      for (int i = 0; i < HRr; i++) whh2[i] = W_hh2[t0 * HRr + i];
      bsum2 = b_ih2[t0] + b_hh2[t0];
    }
    float c2 = 0.f, rv0 = 0.f, rv1 = 0.f;

    for (int t = 0; t < TMAX; ++t) {
      const bool mv = (lane < VOC);
      ull mw = 0;
      for (;;) {
        if (mv) mw = ALD(&PKMSG(ws)[t * VOC + lane]);
        bool ok = !mv || ((unsigned)(mw >> 32) & 0xFFFFu) == (unsigned)(t + 1);
        if (__all(ok)) break;
      }
      const unsigned tag0 = (unsigned)__shfl((int)(mw >> 32), 0);
      const bool done = (tag0 & 0x10000u) != 0;
      float sv2 = mv ? lowf(mw) : 0.f;
      if (act) {
        float a0 = bsum2, a1 = 0.f, a2 = 0.f, a3 = 0.f;
        #pragma unroll
        for (int i = 0; i < VOC; i += 4) {
          a0 += wih2[i    ] * lanebc(sv2, i    );
          a1 += wih2[i + 1] * lanebc(sv2, i + 1);
          a2 += wih2[i + 2] * lanebc(sv2, i + 2);
          a3 += wih2[i + 3] * lanebc(sv2, i + 3);
        }
        #pragma unroll
        for (int i = 0; i < 64; i += 4) {
          a0 += whh2[i    ] * lanebc(rv0, i    );
          a1 += whh2[i + 1] * lanebc(rv0, i + 1);
          a2 += whh2[i + 2] * lanebc(rv0, i + 2);
          a3 += whh2[i + 3] * lanebc(rv0, i + 3);
        }
        #pragma unroll
        for (int i = 0; i < 36; i += 4) {
          a0 += whh2[64 + i    ] * lanebc(rv1, i    );
          a1 += whh2[64 + i + 1] * lanebc(rv1, i + 1);
          a2 += whh2[64 + i + 2] * lanebc(rv1, i + 2);
          a3 += whh2[64 + i + 3] * lanebc(rv1, i + 3);
        }
        gL[t0] = (a0 + a1) + (a2 + a3);
      }
      __syncthreads();
      if (t0 < HRr) {
        float ig = sigf(gL[t0]);
        float fg = sigf(gL[100 + t0]);
        float gg = tanhf(gL[200 + t0]);
        float og = sigf(gL[300 + t0]);
        float cn = fg * c2 + ig * gg; c2 = cn;
        hL[t0] = og * tanhf(cn);
      }
      __syncthreads();
      rv0 = hL[lane];
      rv1 = (lane < 36) ? hL[64 + lane] : 0.f;
      if (done) break;
    }
    if (t0 < HRr) ws[WS_HR + t0] = hL[t0];
  }
}

// ---------------- kernel 2: logits + exp + partial sums (105 MB HBM) -------
// Half-wave per row: lanes 0-24 read row 2i's 400B contiguous, lanes 32-56
// read row 2i+1's (adjacent -> ~800B contiguous per wave-load). 2048 blocks
// x 128 rows. Width-32 shfl reduce; lane0 stores float2 (rows 2i,2i+1).
__global__ __launch_bounds__(256) void k_out(
    const float* __restrict__ W_r, const float* __restrict__ b_r,
    float* __restrict__ ws, float* __restrict__ out) {
  __shared__ float4 h4[25];
  __shared__ float  red[4];
  const int t0 = threadIdx.x;
  if (t0 < 25) h4[t0] = ((const float4*)(ws + WS_HR))[t0];
  __syncthreads();
  const int lane = t0 & 63;
  const int wv   = t0 >> 6;
  const int sl   = lane & 31;
  const int hf   = lane >> 5;
  const int base = blockIdx.x * 128 + wv * 32;
  float accs = 0.f;
  #pragma unroll 4
  for (int i = 0; i < 16; ++i) {
    const int row = base + 2 * i + hf;
    float v = 0.f;
    if (sl < 25) {
      float4 w4 = ((const float4*)W_r)[(size_t)row * 25 + sl];
      float4 hq = h4[sl];
      v = w4.x * hq.x + w4.y * hq.y + w4.z * hq.z + w4.w * hq.w;
    }
    #pragma unroll
    for (int o = 16; o; o >>= 1) v += __shfl_down(v, o, 32);
    float e = 0.f;
    if (sl == 0) { e = expf(v + b_r[row]); accs += e; }
    float eB = __shfl(e, 32);
    if (lane == 0) ((float2*)out)[(base + 2 * i) >> 1] = make_float2(e, eB);
  }
  accs += __shfl_down(accs, 32);     // lane0 += lane32
  if (lane == 0) red[wv] = accs;
  __syncthreads();
  if (t0 == 0)
    atomicAdd(&ws[WS_SUMS + (blockIdx.x & 63)], (red[0] + red[1]) + (red[2] + red[3]));
}

// ---------------- kernel 3: out *= 1/sum -----------------------------------
__global__ __launch_bounds__(256) void k_scale(const float* __restrict__ ws,
                                               float* __restrict__ out) {
  float s = ws[WS_SUMS + (threadIdx.x & 63)];
  #pragma unroll
  for (int o = 1; o < 64; o <<= 1) s += __shfl_xor(s, o);   // identical all lanes
  const float rinv = 1.f / s;
  const int i = blockIdx.x * 256 + threadIdx.x;   // float4 index
  float4 e = ((const float4*)out)[i];
  e.x *= rinv; e.y *= rinv; e.z *= rinv; e.w *= rinv;
  ((float4*)out)[i] = e;
}

extern "C" void kernel_launch(void* const* d_in, const int* in_sizes, int n_in,
                              void* d_out, int out_size, void* d_ws, size_t ws_size,
                              hipStream_t stream) {
  const float* x     = (const float*)d_in[0];
  const float* gum   = (const float*)d_in[1];
  const float* W_s1  = (const float*)d_in[2];
  const float* b_s1  = (const float*)d_in[3];
  const float* W_ih1 = (const float*)d_in[4];
  const float* W_hh1 = (const float*)d_in[5];
  const float* b_ih1 = (const float*)d_in[6];
  const float* b_hh1 = (const float*)d_in[7];
  const float* W_p   = (const float*)d_in[8];
  const float* b_p   = (const float*)d_in[9];
  const float* W_ih2 = (const float*)d_in[10];
  const float* W_hh2 = (const float*)d_in[11];
  const float* b_ih2 = (const float*)d_in[12];
  const float* b_hh2 = (const float*)d_in[13];
  const float* W_r   = (const float*)d_in[14];
  const float* b_r   = (const float*)d_in[15];
  float* ws  = (float*)d_ws;
  float* out = (float*)d_out;

  // zero packed tag regions + sum slots (ws re-poisoned 0xAA every launch)
  (void)hipMemsetAsync(d_ws, 0, WS_ZERO_BYTES, stream);
  k_sender<<<KS + 1,   512, 0, stream>>>(x, W_s1, b_s1, gum, W_ih1, W_hh1,
                                         b_ih1, b_hh1, W_p, b_p,
                                         W_ih2, W_hh2, b_ih2, b_hh2, ws);
  k_out   <<<NCLS/128, 256, 0, stream>>>(W_r, b_r, ws, out);
  k_scale <<<NCLS/1024,256, 0, stream>>>(ws, out);
}

// Round 6
// 315.656 us; speedup vs baseline: 1.0292x; 1.0292x over previous
//
#include <hip/hip_runtime.h>
#include <math.h>

// Problem constants (from reference)
#define HS    250      // sender hidden
#define HRr   100      // receiver hidden
#define VOC   40       // vocab, EOS = 39
#define TMAX  30       // max message length
#define NCLS  262144   // output classes
#define KS    10       // sender blocks (each owns 25 h-rows = 100 gate rows)
#define RPB   25       // h-rows per sender block

typedef unsigned long long ull;

// ws layout. Packed (tag<<32 | float) regions first, 8B-aligned:
//   PK_NH : ull[2][256]  h exchange, double-buffered by tag parity
//   PK_LP : ull[2][400]  logit partials, double-buffered
//   PK_MSG: ull[30*40]   message symbols (tag carries done bit)
// Floats after: WS_SUMS float[64] @byte 20096; WS_HR float[100] @byte 20352.
#define PKNH(wsp, par) ((ull*)(wsp) + (size_t)(par) * 256)
#define PKLP(wsp, par) ((ull*)(wsp) + 512 + (size_t)(par) * 400)
#define PKMSG(wsp)     ((ull*)(wsp) + 1312)
#define WS_SUMS 5024   // float index
#define WS_HR   5088   // float index (byte 20352, 16B aligned)
#define WS_ZERO_BYTES 20352

#define AST(p, v) __hip_atomic_store((p), (v), __ATOMIC_RELAXED, __HIP_MEMORY_SCOPE_AGENT)
#define ALD(p)    __hip_atomic_load((p), __ATOMIC_RELAXED, __HIP_MEMORY_SCOPE_AGENT)

__device__ __forceinline__ float sigf(float x) { return 1.f / (1.f + expf(-x)); }
__device__ __forceinline__ float lanebc(float v, int l) {
  return __int_as_float(__builtin_amdgcn_readlane(__float_as_int(v), l));
}
__device__ __forceinline__ ull packtv(unsigned tag, float v) {
  return ((ull)tag << 32) | (ull)__float_as_uint(v);
}
__device__ __forceinline__ float lowf(ull w) { return __uint_as_float((unsigned)w); }

#define SENDER_GATES(P, HV)                                   \
  {                                                           \
    _Pragma("unroll")                                         \
    for (int i = 0; i < 64; i += 4) {                         \
      a0 += whh[i    ] * lanebc(HV, i    );                   \
      a1 += whh[i + 1] * lanebc(HV, i + 1);                   \
      a2 += whh[i + 2] * lanebc(HV, i + 2);                   \
      a3 += whh[i + 3] * lanebc(HV, i + 3);                   \
    }                                                         \
    _Pragma("unroll")                                         \
    for (int i = 0; i < 10; i += 2) {                         \
      a0 += wih[i    ] * lanebc(sv, (P) * 10 + i    );        \
      a1 += wih[i + 1] * lanebc(sv, (P) * 10 + i + 1);        \
    }                                                         \
  }

#define RED(x) ((part[(x)] + part[100 + (x)]) + (part[200 + (x)] + part[300 + (x)]))

// ---------------- fused kernel: h0 + sender (blocks 0..9) + receiver (10) --
__global__ __launch_bounds__(512, 2) void k_sender(
    const float* __restrict__ x,
    const float* __restrict__ W_s1,  const float* __restrict__ b_s1,
    const float* __restrict__ gum,
    const float* __restrict__ W_ih1, const float* __restrict__ W_hh1,
    const float* __restrict__ b_ih1, const float* __restrict__ b_hh1,
    const float* __restrict__ W_p,   const float* __restrict__ b_p,
    const float* __restrict__ W_ih2, const float* __restrict__ W_hh2,
    const float* __restrict__ b_ih2, const float* __restrict__ b_hh2,
    float* __restrict__ ws) {
  __shared__ float part[400];
  __shared__ float h0L[32];
  __shared__ float hx[256];     // wave-0 broadcast of exchanged h
  __shared__ float lpx[400];    // wave-0 broadcast of exchanged lp
  __shared__ float symx[VOC];   // receiver
  __shared__ int   doneL;       // receiver
  __shared__ float gL[400];     // receiver
  __shared__ float hL[HRr];     // receiver

  const int b    = blockIdx.x;
  const int t0   = threadIdx.x;
  const int lane = t0 & 63;
  const int w    = t0 >> 6;

  if (b < KS) {
    // ================= SENDER =================
    const int p    = w & 3;
    const int lr   = ((w >> 2) << 6) + lane;   // 0..127
    const bool gact = (lr < 100);
    const int gi   = lr / 25, rr = lr % 25;
    const int grow = gi * 250 + b * RPB + rr;  // global gate row

    float whh[64], wih[10], bsum = 0.f;
    if (gact) {
      #pragma unroll
      for (int i = 0; i < 64; i++) {
        int k = p * 64 + i;
        whh[i] = (k < HS) ? W_hh1[(size_t)grow * HS + k] : 0.f;
      }
      #pragma unroll
      for (int i = 0; i < 10; i++) wih[i] = W_ih1[grow * VOC + p * 10 + i];
      bsum = b_ih1[grow] + b_hh1[grow];
    }
    // wave 0: W_p slice (lane j holds W_p[j, b*25 .. +25))
    float wps[RPB];
    if (w == 0) {
      #pragma unroll
      for (int r = 0; r < RPB; r++)
        wps[r] = (lane < VOC) ? W_p[lane * HS + b * RPB + r] : 0.f;
    }
    const float bpv = (lane < VOC) ? b_p[lane] : 0.f;   // all waves (softmax)

    // ---- pre-step: h0 = relu(W_s1 @ x + b_s1), this block's 25 rows ----
    {
      const int nr = (w == 7) ? 4 : 3;
      for (int j = 0; j < nr; ++j) {
        const int r = 3 * w + j;
        const float4* wr = (const float4*)(W_s1 + (size_t)(b * RPB + r) * 4096);
        const float4* xr = (const float4*)x;
        float a0 = 0.f, a1 = 0.f, a2 = 0.f, a3 = 0.f;
        #pragma unroll
        for (int q = 0; q < 16; ++q) {
          float4 w4 = wr[lane + (q << 6)], x4 = xr[lane + (q << 6)];
          a0 += w4.x * x4.x; a1 += w4.y * x4.y; a2 += w4.z * x4.z; a3 += w4.w * x4.w;
        }
        float acc = (a0 + a1) + (a2 + a3);
        #pragma unroll
        for (int o = 32; o; o >>= 1) acc += __shfl_down(acc, o);
        if (lane == 0) h0L[r] = acc + b_s1[b * RPB + r];
      }
    }
    __syncthreads();
    if (w == 0 && lane < RPB) {    // publish h(0), tag 1 (parity 1)
      float hn0 = fmaxf(h0L[lane], 0.f);
      AST(&PKNH(ws, 1)[b * RPB + lane], packtv(1u, hn0));
    }

    float c  = 0.f;   // cell state, wave0 lanes<25
    float sv = 0.f;   // current symbol, lane-distributed
    const bool h3v = (192 + lane) < HS;   // lane < 58
    const bool l6v = lane < (400 - 384);  // lane < 16

    for (int s = 0; s <= TMAX; ++s) {
      float gv = 0.f;
      if (s > 0 && lane < VOC) gv = gum[(s - 1) * VOC + lane];

      // ---- wave-0-only merged self-tag spin: h(s) + lp(s-1..), tag s+1 ----
      if (w == 0) {
        const unsigned need = (unsigned)(s + 1);
        const int par = (s + 1) & 1;
        const ull* nhp = PKNH(ws, par);
        const ull* lpp = PKLP(ws, par);
        const bool lpact = (s > 0);
        const ull dummy = (ull)need << 32;
        ull hw0, hw1, hw2, hw3;
        ull lw0 = 0, lw1 = 0, lw2 = 0, lw3 = 0, lw4 = 0, lw5 = 0, lw6 = 0;
        for (;;) {
          hw0 = ALD(&nhp[lane]);
          hw1 = ALD(&nhp[64 + lane]);
          hw2 = ALD(&nhp[128 + lane]);
          hw3 = h3v ? ALD(&nhp[192 + lane]) : dummy;
          bool ok = (unsigned)(hw0 >> 32) == need && (unsigned)(hw1 >> 32) == need &&
                    (unsigned)(hw2 >> 32) == need && (unsigned)(hw3 >> 32) == need;
          if (lpact) {
            lw0 = ALD(&lpp[lane]);        lw1 = ALD(&lpp[64 + lane]);
            lw2 = ALD(&lpp[128 + lane]);  lw3 = ALD(&lpp[192 + lane]);
            lw4 = ALD(&lpp[256 + lane]);  lw5 = ALD(&lpp[320 + lane]);
            lw6 = l6v ? ALD(&lpp[384 + lane]) : dummy;
            ok = ok && (unsigned)(lw0 >> 32) == need && (unsigned)(lw1 >> 32) == need &&
                       (unsigned)(lw2 >> 32) == need && (unsigned)(lw3 >> 32) == need &&
                       (unsigned)(lw4 >> 32) == need && (unsigned)(lw5 >> 32) == need &&
                       (unsigned)(lw6 >> 32) == need;
          }
          if (__all(ok)) break;
        }
        hx[lane] = lowf(hw0); hx[64 + lane] = lowf(hw1); hx[128 + lane] = lowf(hw2);
        if (h3v) hx[192 + lane] = lowf(hw3);
        if (lpact) {
          lpx[lane] = lowf(lw0);        lpx[64 + lane] = lowf(lw1);
          lpx[128 + lane] = lowf(lw2);  lpx[192 + lane] = lowf(lw3);
          lpx[256 + lane] = lowf(lw4);  lpx[320 + lane] = lowf(lw5);
          if (l6v) lpx[384 + lane] = lowf(lw6);
        }
      }
      __syncthreads();   // #2: broadcast hx/lpx

      float hv0 = hx[lane], hv1 = hx[64 + lane], hv2 = hx[128 + lane];
      float hv3 = h3v ? hx[192 + lane] : 0.f;

      // ---- per-wave softmax of step s-1 (redundant across waves) ----
      if (s > 0) {
        float lg = -INFINITY;
        if (lane < VOC) {
          float acc = bpv + gv;
          #pragma unroll
          for (int m = 0; m < KS; ++m) acc += lpx[m * VOC + lane];
          lg = acc;
        }
        float v = lg; int bi = lane;
        #pragma unroll
        for (int o = 32; o; o >>= 1) {      // first-max argmax (ties -> lower lane)
          float ov = __shfl_down(v, o);
          int   oi = __shfl_down(bi, o);
          if (ov > v) { v = ov; bi = oi; }
        }
        float m  = __shfl(v, 0);
        int  idx = __shfl(bi, 0);
        float e = (lane < VOC) ? expf(lg - m) : 0.f;
        float ssum = e;
        #pragma unroll
        for (int o = 32; o; o >>= 1) ssum += __shfl_down(ssum, o);
        ssum = __shfl(ssum, 0);
        float soft = e / ssum;
        float hard = (lane == idx) ? 1.f : 0.f;
        float st   = (hard + soft) - soft;           // exact ST forward ordering
        const bool last = (s - 1 == TMAX - 1);
        float emit = last ? ((lane == VOC - 1) ? 1.f : 0.f) : st;
        const bool done = (idx == VOC - 1) || last;
        if (b == 0 && w == 0 && lane < VOC)
          AST(&PKMSG(ws)[(s - 1) * VOC + lane],
              packtv((unsigned)s | (done ? 0x10000u : 0u), emit));
        sv = (lane < VOC) ? emit : 0.f;
        if (done) break;                             // uniform across waves/blocks
      }

      // ---- gate partials: 100 rows x k-slice, all 8 waves ----
      if (gact) {
        float a0 = bsum, a1 = 0.f, a2 = 0.f, a3 = 0.f;
        if      (p == 0) SENDER_GATES(0, hv0)
        else if (p == 1) SENDER_GATES(1, hv1)
        else if (p == 2) SENDER_GATES(2, hv2)
        else             SENDER_GATES(3, hv3)
        part[p * 100 + lr] = (a0 + a1) + (a2 + a3);
      }
      __syncthreads();   // #1

      // ---- wave-0: reduce, h/c update, logit partial, publish tag s+2 ----
      if (w == 0) {
        float gi_ = RED(lane < RPB ? lane : 0);
        float gf_ = RED(25 + (lane < RPB ? lane : 0));
        float gg_ = RED(50 + (lane < RPB ? lane : 0));
        float go_ = RED(75 + (lane < RPB ? lane : 0));
        float ig = sigf(gi_), fg = sigf(gf_), gg = tanhf(gg_), og = sigf(go_);
        float cn = fg * c + ig * gg; c = cn;
        float hn = og * tanhf(cn);
        float lpsum = 0.f;
        #pragma unroll
        for (int r = 0; r < RPB; ++r) lpsum += wps[r] * lanebc(hn, r);
        const unsigned nt = (unsigned)(s + 2);
        const int np = (s + 2) & 1;
        if (lane < RPB) AST(&PKNH(ws, np)[b * RPB + lane], packtv(nt, hn));
        if (lane < VOC) AST(&PKLP(ws, np)[b * VOC + lane], packtv(nt, lpsum));
      }
    }
  } else {
    // ================= RECEIVER (concurrent consumer) =================
    const bool act = (t0 < 400);
    float wih2[VOC], whh2[HRr], bsum2 = 0.f;
    if (act) {
      #pragma unroll
      for (int i = 0; i < VOC; i++) wih2[i] = W_ih2[t0 * VOC + i];
      #pragma unroll
      for (int i = 0; i < HRr; i++) whh2[i] = W_hh2[t0 * HRr + i];
      bsum2 = b_ih2[t0] + b_hh2[t0];
    }
    float c2 = 0.f, rv0 = 0.f, rv1 = 0.f;

    for (int t = 0; t < TMAX; ++t) {
      // ---- wave-0-only spin on tagged message words ----
      if (w == 0) {
        const bool mv = (lane < VOC);
        ull mw = 0;
        for (;;) {
          if (mv) mw = ALD(&PKMSG(ws)[t * VOC + lane]);
          bool ok = !mv || ((unsigned)(mw >> 32) & 0xFFFFu) == (unsigned)(t + 1);
          if (__all(ok)) break;
        }
        if (mv) symx[lane] = lowf(mw);
        if (lane == 0) doneL = (int)(((unsigned)(mw >> 32)) >> 16);
      }
      __syncthreads();
      const bool done = (doneL != 0);
      float sv2 = (lane < VOC) ? symx[lane] : 0.f;
      if (act) {
        float a0 = bsum2, a1 = 0.f, a2 = 0.f, a3 = 0.f;
        #pragma unroll
        for (int i = 0; i < VOC; i += 4) {
          a0 += wih2[i    ] * lanebc(sv2, i    );
          a1 += wih2[i + 1] * lanebc(sv2, i + 1);
          a2 += wih2[i + 2] * lanebc(sv2, i + 2);
          a3 += wih2[i + 3] * lanebc(sv2, i + 3);
        }
        #pragma unroll
        for (int i = 0; i < 64; i += 4) {
          a0 += whh2[i    ] * lanebc(rv0, i    );
          a1 += whh2[i + 1] * lanebc(rv0, i + 1);
          a2 += whh2[i + 2] * lanebc(rv0, i + 2);
          a3 += whh2[i + 3] * lanebc(rv0, i + 3);
        }
        #pragma unroll
        for (int i = 0; i < 36; i += 4) {
          a0 += whh2[64 + i    ] * lanebc(rv1, i    );
          a1 += whh2[64 + i + 1] * lanebc(rv1, i + 1);
          a2 += whh2[64 + i + 2] * lanebc(rv1, i + 2);
          a3 += whh2[64 + i + 3] * lanebc(rv1, i + 3);
        }
        gL[t0] = (a0 + a1) + (a2 + a3);
      }
      __syncthreads();
      if (t0 < HRr) {
        float ig = sigf(gL[t0]);
        float fg = sigf(gL[100 + t0]);
        float gg = tanhf(gL[200 + t0]);
        float og = sigf(gL[300 + t0]);
        float cn = fg * c2 + ig * gg; c2 = cn;
        hL[t0] = og * tanhf(cn);
      }
      __syncthreads();
      rv0 = hL[lane];
      rv1 = (lane < 36) ? hL[64 + lane] : 0.f;
      if (done) break;
    }
    if (t0 < HRr) ws[WS_HR + t0] = hL[t0];
  }
}

// ---------------- kernel 2: logits + exp + partial sums (105 MB HBM) -------
__global__ __launch_bounds__(256) void k_out(
    const float* __restrict__ W_r, const float* __restrict__ b_r,
    float* __restrict__ ws, float* __restrict__ out) {
  __shared__ float4 h4[25];
  __shared__ float  red[4];
  const int t0 = threadIdx.x;
  if (t0 < 25) h4[t0] = ((const float4*)(ws + WS_HR))[t0];
  __syncthreads();
  const int lane = t0 & 63;
  const int wv   = t0 >> 6;
  const int sl   = lane & 31;
  const int hf   = lane >> 5;
  const int base = blockIdx.x * 128 + wv * 32;
  float accs = 0.f;
  #pragma unroll 4
  for (int i = 0; i < 16; ++i) {
    const int row = base + 2 * i + hf;
    float v = 0.f;
    if (sl < 25) {
      float4 w4 = ((const float4*)W_r)[(size_t)row * 25 + sl];
      float4 hq = h4[sl];
      v = w4.x * hq.x + w4.y * hq.y + w4.z * hq.z + w4.w * hq.w;
    }
    #pragma unroll
    for (int o = 16; o; o >>= 1) v += __shfl_down(v, o, 32);
    float e = 0.f;
    if (sl == 0) { e = expf(v + b_r[row]); accs += e; }
    float eB = __shfl(e, 32);
    if (lane == 0) ((float2*)out)[(base + 2 * i) >> 1] = make_float2(e, eB);
  }
  accs += __shfl_down(accs, 32);     // lane0 += lane32
  if (lane == 0) red[wv] = accs;
  __syncthreads();
  if (t0 == 0)
    atomicAdd(&ws[WS_SUMS + (blockIdx.x & 63)], (red[0] + red[1]) + (red[2] + red[3]));
}

// ---------------- kernel 3: out *= 1/sum -----------------------------------
__global__ __launch_bounds__(256) void k_scale(const float* __restrict__ ws,
                                               float* __restrict__ out) {
  float s = ws[WS_SUMS + (threadIdx.x & 63)];
  #pragma unroll
  for (int o = 1; o < 64; o <<= 1) s += __shfl_xor(s, o);   // identical all lanes
  const float rinv = 1.f / s;
  const int i = blockIdx.x * 256 + threadIdx.x;   // float4 index
  float4 e = ((const float4*)out)[i];
  e.x *= rinv; e.y *= rinv; e.z *= rinv; e.w *= rinv;
  ((float4*)out)[i] = e;
}

extern "C" void kernel_launch(void* const* d_in, const int* in_sizes, int n_in,
                              void* d_out, int out_size, void* d_ws, size_t ws_size,
                              hipStream_t stream) {
  const float* x     = (const float*)d_in[0];
  const float* gum   = (const float*)d_in[1];
  const float* W_s1  = (const float*)d_in[2];
  const float* b_s1  = (const float*)d_in[3];
  const float* W_ih1 = (const float*)d_in[4];
  const float* W_hh1 = (const float*)d_in[5];
  const float* b_ih1 = (const float*)d_in[6];
  const float* b_hh1 = (const float*)d_in[7];
  const float* W_p   = (const float*)d_in[8];
  const float* b_p   = (const float*)d_in[9];
  const float* W_ih2 = (const float*)d_in[10];
  const float* W_hh2 = (const float*)d_in[11];
  const float* b_ih2 = (const float*)d_in[12];
  const float* b_hh2 = (const float*)d_in[13];
  const float* W_r   = (const float*)d_in[14];
  const float* b_r   = (const float*)d_in[15];
  float* ws  = (float*)d_ws;
  float* out = (float*)d_out;

  // zero packed tag regions + sum slots (ws re-poisoned 0xAA every launch)
  (void)hipMemsetAsync(d_ws, 0, WS_ZERO_BYTES, stream);
  k_sender<<<KS + 1,   512, 0, stream>>>(x, W_s1, b_s1, gum, W_ih1, W_hh1,
                                         b_ih1, b_hh1, W_p, b_p,
                                         W_ih2, W_hh2, b_ih2, b_hh2, ws);
  k_out   <<<NCLS/128, 256, 0, stream>>>(W_r, b_r, ws, out);
  k_scale <<<NCLS/1024,256, 0, stream>>>(ws, out);
}